// Round 4
// baseline (764.048 us; speedup 1.0000x reference)
//
#include <hip/hip_runtime.h>

typedef float f32x4 __attribute__((ext_vector_type(4)));
typedef short bf16x8 __attribute__((ext_vector_type(8)));
typedef unsigned short u16;

#define B_SZ 4
#define S_SZ 4096
#define H_SZ 1024
#define F_SZ 4096
#define CHUNK_SZ 512
#define NCHUNK 8
#define MCH 2048            // rows per chunk (B*CHUNK)
#define LRATE 0.001f
#define NSPLIT 4            // split-K factor for GEMM2

__device__ __forceinline__ u16 f2bf(float f) {
  unsigned u = __float_as_uint(f);
  u += 0x7FFFu + ((u >> 16) & 1u);   // round-to-nearest-even
  return (u16)(u >> 16);
}
__device__ __forceinline__ float bf2f(u16 u) {
  return __uint_as_float(((unsigned)u) << 16);
}

__device__ __forceinline__ void gload_lds16(const void* g, void* l) {
  __builtin_amdgcn_global_load_lds(
      (const __attribute__((address_space(1))) unsigned int*)g,
      (__attribute__((address_space(3))) unsigned int*)l, 16, 0, 0);
}

// ---------------- converts ----------------

__global__ __launch_bounds__(256) void k_init(float* scal) {
  if (threadIdx.x == 0) { scal[0] = 1.f; scal[1] = 0.f; }
}

__global__ __launch_bounds__(256) void k_cvt_x(const float* __restrict__ x,
                                               u16* __restrict__ xb) {
  size_t i = ((size_t)blockIdx.x * 256 + threadIdx.x) * 8;
  float4 v0 = *(const float4*)(x + i);
  float4 v1 = *(const float4*)(x + i + 4);
  union { u16 u[8]; bf16x8 v; } o;
  o.u[0] = f2bf(v0.x); o.u[1] = f2bf(v0.y); o.u[2] = f2bf(v0.z); o.u[3] = f2bf(v0.w);
  o.u[4] = f2bf(v1.x); o.u[5] = f2bf(v1.y); o.u[6] = f2bf(v1.z); o.u[7] = f2bf(v1.w);
  *(bf16x8*)(xb + i) = o.v;
}

// W [R][C] fp32  ->  Wt [C][R] bf16
__global__ __launch_bounds__(256) void k_transpose_cvt(const float* __restrict__ W,
                                                       u16* __restrict__ Wt,
                                                       int R, int C) {
  __shared__ float tile[32][33];
  int tx = threadIdx.x & 31, ty = threadIdx.x >> 5;
  int r0 = blockIdx.y << 5, c0 = blockIdx.x << 5;
#pragma unroll
  for (int i = 0; i < 4; i++)
    tile[ty + i * 8][tx] = W[(size_t)(r0 + ty + i * 8) * C + c0 + tx];
  __syncthreads();
#pragma unroll
  for (int i = 0; i < 4; i++)
    Wt[(size_t)(c0 + ty + i * 8) * R + r0 + tx] = f2bf(tile[tx][ty + i * 8]);
}

// ---------------- GEMM 1: G = Xc@W0, U = Xc@W2, fused SwiGLU -> h (bf16) ----------------
// tile 128(M) x 64(N), BK=32 DOUBLE-BUFFERED (LDS stays 32KB -> 4 blocks/CU),
// slot-XOR swizzle (2-way = free), prefetch-before-compute, XCD-bijective swizzle.
__global__ __launch_bounds__(256) void k_gemm_gu(
    const u16* __restrict__ xb,   // [B][S][H] bf16
    const u16* __restrict__ w0t,  // [F][H] bf16 (w0^T)
    const u16* __restrict__ w2t,  // [F][H]
    u16* __restrict__ hbuf,       // [2048][F] bf16
    const float* __restrict__ scal, int chunk) {
  __shared__ __align__(16) u16 sA[2][128 * 32];   // 2 x 8KB
  __shared__ __align__(16) u16 sB0[2][64 * 32];   // 2 x 4KB
  __shared__ __align__(16) u16 sB2[2][64 * 32];   // 2 x 4KB

  int t = threadIdx.x;
  int lane = t & 63, wid = t >> 6;
  int wm = wid >> 1, wn = wid & 1;

  // XCD-bijective swizzle: 1024 wgs / 8 XCDs -> contiguous 128-wg chunk per XCD
  int orig = blockIdx.x + (gridDim.x * blockIdx.y);
  int nwg = gridDim.x * gridDim.y;
  int wg = (orig & 7) * (nwg >> 3) + (orig >> 3);
  int tm = wg & 15, tn = wg >> 4;

  int gm0 = tm << 7;               // chunk-local row 0 of tile
  int bb = gm0 >> 9;               // batch (tile never crosses batch)
  int pos0 = gm0 & 511;
  const u16* Abase = xb + ((size_t)bb * S_SZ + (size_t)chunk * CHUNK_SZ + pos0) * H_SZ;

  // staging (BK=32, row = 64B = 4 slots of 16B): thread t -> row t>>2, slot t&3.
  // source col = (slot ^ ((row>>1)&3))*8 so LDS[row][slot] holds col (slot^((row>>1)&3)).
  int srow = t >> 2;
  int scol = (((t & 3) ^ ((srow >> 1) & 3)) << 3);   // elements
  const u16* aSrc  = Abase + (size_t)srow * H_SZ + scol;
  const u16* b0Src = w0t + ((size_t)(tn << 6) + srow) * H_SZ + scol;
  const u16* b2Src = w2t + ((size_t)(tn << 6) + srow) * H_SZ + scol;

  f32x4 acc0[4][2], acc2[4][2];
#pragma unroll
  for (int i = 0; i < 4; i++)
#pragma unroll
    for (int j = 0; j < 2; j++)
#pragma unroll
      for (int k = 0; k < 4; k++) { acc0[i][j][k] = 0.f; acc2[i][j][k] = 0.f; }

  // read side: row = base + (lane&15), slot = (lane>>4) ^ ((row>>1)&3);
  // base is a multiple of 16 so (row>>1)&3 == ((lane&15)>>1)&3 — per-lane constant.
  int rsl = (lane >> 4) ^ (((lane & 15) >> 1) & 3);
  const int aO = ((wm << 6) + (lane & 15)) * 64 + rsl * 16;   // bytes
  const int bO = ((wn << 5) + (lane & 15)) * 64 + rsl * 16;

#define GU_PREFETCH(b)                                                     \
  {                                                                        \
    gload_lds16(aSrc, (char*)sA + (b)*8192 + t * 16);                      \
    gload_lds16(aSrc + (size_t)64 * H_SZ, (char*)sA + (b)*8192 + 4096 + t * 16); \
    gload_lds16(b0Src, (char*)sB0 + (b)*4096 + t * 16);                    \
    gload_lds16(b2Src, (char*)sB2 + (b)*4096 + t * 16);                    \
    aSrc += 32; b0Src += 32; b2Src += 32;                                  \
  }

#define GU_COMPUTE(b)                                                      \
  {                                                                        \
    const char* aB  = (const char*)sA  + (b)*8192;                         \
    const char* b0B = (const char*)sB0 + (b)*4096;                         \
    const char* b2B = (const char*)sB2 + (b)*4096;                         \
    bf16x8 av[4], b0v[2], b2v[2];                                          \
    _Pragma("unroll")                                                      \
    for (int fr = 0; fr < 4; fr++) av[fr] = *(const bf16x8*)(aB + aO + fr * 1024); \
    _Pragma("unroll")                                                      \
    for (int fc = 0; fc < 2; fc++) {                                       \
      b0v[fc] = *(const bf16x8*)(b0B + bO + fc * 1024);                    \
      b2v[fc] = *(const bf16x8*)(b2B + bO + fc * 1024);                    \
    }                                                                      \
    _Pragma("unroll")                                                      \
    for (int fr = 0; fr < 4; fr++)                                         \
      _Pragma("unroll")                                                    \
      for (int fc = 0; fc < 2; fc++) {                                     \
        acc0[fr][fc] = __builtin_amdgcn_mfma_f32_16x16x32_bf16(av[fr], b0v[fc], acc0[fr][fc], 0, 0, 0); \
        acc2[fr][fc] = __builtin_amdgcn_mfma_f32_16x16x32_bf16(av[fr], b2v[fc], acc2[fr][fc], 0, 0, 0); \
      }                                                                    \
  }

  // prologue: stage K-step 0 into buf 0
  GU_PREFETCH(0);
  __syncthreads();

#pragma unroll 1
  for (int step = 0; step < 32; step += 2) {
    if (step + 1 < 32) GU_PREFETCH(1);
    GU_COMPUTE(0);
    __syncthreads();
    if (step + 2 < 32) GU_PREFETCH(0);
    GU_COMPUTE(1);
    __syncthreads();
  }

  float D = scal[0];
#pragma unroll
  for (int fr = 0; fr < 4; fr++)
#pragma unroll
    for (int fc = 0; fc < 2; fc++) {
      int row0 = (tm << 7) + (wm << 6) + (fr << 4) + ((lane >> 4) << 2);
      int col = (tn << 6) + (wn << 5) + (fc << 4) + (lane & 15);
#pragma unroll
      for (int j = 0; j < 4; j++) {
        float g = D * acc0[fr][fc][j];
        float u = D * acc2[fr][fc][j];
        float sil = g / (1.f + __expf(-g));
        hbuf[(size_t)(row0 + j) * F_SZ + col] = f2bf(sil * u);
      }
    }
}

// ---------------- GEMM 2 (split-K): pbuf[kz] = h[:,kz*1024:+1024] @ w1t slice ----------------
// tile 128x64, BK=32 double-buffered (LDS 24KB), no XCD remap (round-2 behavior).
__global__ __launch_bounds__(256) void k_gemm_out(
    const u16* __restrict__ hbuf,  // [2048][F]
    const u16* __restrict__ w1t,   // [H][F] (w1^T)
    u16* __restrict__ pbuf) {      // [NSPLIT][2048][1024] bf16 partials
  __shared__ __align__(16) u16 sA[2][128 * 32];
  __shared__ __align__(16) u16 sB[2][64 * 32];

  int t = threadIdx.x;
  int lane = t & 63, wid = t >> 6;
  int wm = wid >> 1, wn = wid & 1;
  int tm = blockIdx.x, tn = blockIdx.y, kz = blockIdx.z;

  int srow = t >> 2;
  int scol = (((t & 3) ^ ((srow >> 1) & 3)) << 3);
  const u16* aSrc = hbuf + ((size_t)(tm << 7) + srow) * F_SZ + kz * 1024 + scol;
  const u16* bSrc = w1t + ((size_t)(tn << 6) + srow) * F_SZ + kz * 1024 + scol;

  f32x4 acc[4][2];
#pragma unroll
  for (int i = 0; i < 4; i++)
#pragma unroll
    for (int j = 0; j < 2; j++)
#pragma unroll
      for (int k = 0; k < 4; k++) acc[i][j][k] = 0.f;

  int rsl = (lane >> 4) ^ (((lane & 15) >> 1) & 3);
  const int aO = ((wm << 6) + (lane & 15)) * 64 + rsl * 16;
  const int bO = ((wn << 5) + (lane & 15)) * 64 + rsl * 16;

#define GO_PREFETCH(b)                                                     \
  {                                                                        \
    gload_lds16(aSrc, (char*)sA + (b)*8192 + t * 16);                      \
    gload_lds16(aSrc + (size_t)64 * F_SZ, (char*)sA + (b)*8192 + 4096 + t * 16); \
    gload_lds16(bSrc, (char*)sB + (b)*4096 + t * 16);                      \
    aSrc += 32; bSrc += 32;                                                \
  }

#define GO_COMPUTE(b)                                                      \
  {                                                                        \
    const char* aB = (const char*)sA + (b)*8192;                           \
    const char* bB = (const char*)sB + (b)*4096;                           \
    bf16x8 av[4], bv[2];                                                   \
    _Pragma("unroll")                                                      \
    for (int fr = 0; fr < 4; fr++) av[fr] = *(const bf16x8*)(aB + aO + fr * 1024); \
    _Pragma("unroll")                                                      \
    for (int fc = 0; fc < 2; fc++) bv[fc] = *(const bf16x8*)(bB + bO + fc * 1024); \
    _Pragma("unroll")                                                      \
    for (int fr = 0; fr < 4; fr++)                                         \
      _Pragma("unroll")                                                    \
      for (int fc = 0; fc < 2; fc++)                                       \
        acc[fr][fc] = __builtin_amdgcn_mfma_f32_16x16x32_bf16(av[fr], bv[fc], acc[fr][fc], 0, 0, 0); \
  }

  GO_PREFETCH(0);
  __syncthreads();

#pragma unroll 1
  for (int step = 0; step < 32; step += 2) {
    if (step + 1 < 32) GO_PREFETCH(1);
    GO_COMPUTE(0);
    __syncthreads();
    if (step + 2 < 32) GO_PREFETCH(0);
    GO_COMPUTE(1);
    __syncthreads();
  }

#pragma unroll
  for (int fr = 0; fr < 4; fr++)
#pragma unroll
    for (int fc = 0; fc < 2; fc++) {
      int row0 = (tm << 7) + (wm << 6) + (fr << 4) + ((lane >> 4) << 2);
      int col = (tn << 6) + (wn << 5) + (fc << 4) + (lane & 15);
#pragma unroll
      for (int j = 0; j < 4; j++)
        pbuf[((size_t)kz * MCH + row0 + j) * 1024 + col] = f2bf(acc[fr][fc][j]);
    }
}

// ---------------- epilogue: sum split-K partials, scale by D, write out, error reduce ----------------
__global__ __launch_bounds__(256) void k_epilogue(
    const u16* __restrict__ pbuf, const float* __restrict__ x,
    float* __restrict__ out, const float* __restrict__ scal,
    float* __restrict__ partials, int chunk) {
  __shared__ float red[256];
  int t = threadIdx.x;
  size_t base = ((size_t)blockIdx.x * 256 + t) * 8;   // elem index in [2048][1024]
  int row = (int)(base >> 10);
  int col = (int)(base & 1023);
  float D = scal[0];

  float s[8] = {0.f, 0.f, 0.f, 0.f, 0.f, 0.f, 0.f, 0.f};
#pragma unroll
  for (int kz = 0; kz < NSPLIT; kz++) {
    union { bf16x8 v; u16 u[8]; } p;
    p.v = *(const bf16x8*)(pbuf + (size_t)kz * MCH * 1024 + base);
#pragma unroll
    for (int j = 0; j < 8; j++) s[j] += bf2f(p.u[j]);
  }

  int bb = row >> 9, pos = row & 511;
  size_t off = ((size_t)bb * S_SZ + (size_t)chunk * CHUNK_SZ + pos) * H_SZ + col;
  float4 x0 = *(const float4*)(x + off);
  float4 x1 = *(const float4*)(x + off + 4);
  float xv[8] = {x0.x, x0.y, x0.z, x0.w, x1.x, x1.y, x1.z, x1.w};
  float ov[8];
  float psum = 0.f;
#pragma unroll
  for (int j = 0; j < 8; j++) {
    ov[j] = D * s[j];
    float e = ov[j] - xv[j];
    psum += e * e;
  }
  *(float4*)(out + off) = make_float4(ov[0], ov[1], ov[2], ov[3]);
  *(float4*)(out + off + 4) = make_float4(ov[4], ov[5], ov[6], ov[7]);

  red[t] = psum;
  __syncthreads();
  for (int s2 = 128; s2 > 0; s2 >>= 1) {
    if (t < s2) red[t] += red[t + s2];
    __syncthreads();
  }
  if (t == 0) partials[blockIdx.x] = red[0];
}

// ---------------- scalar chain update ----------------
__global__ __launch_bounds__(256) void k_update(float* scal, const float* __restrict__ partials,
                                                float* lossout, int chunk) {
  __shared__ float red[256];
  int t = threadIdx.x;
  float s = 0.f;
  for (int i = t; i < 1024; i += 256) s += partials[i];
  red[t] = s;
  __syncthreads();
  for (int s2 = 128; s2 > 0; s2 >>= 1) {
    if (t < s2) red[t] += red[t + s2];
    __syncthreads();
  }
  if (t == 0) {
    float loss = red[0] / (float)((size_t)MCH * H_SZ);
    float total = scal[1] + loss;
    scal[1] = total;
    scal[0] = scal[0] * (1.f - LRATE * loss);
    if (chunk == NCHUNK - 1) lossout[0] = total / (float)NCHUNK;
  }
}

// ---------------- launch ----------------
extern "C" void kernel_launch(void* const* d_in, const int* in_sizes, int n_in,
                              void* d_out, int out_size, void* d_ws, size_t ws_size,
                              hipStream_t stream) {
  const float* x = (const float*)d_in[0];
  const float* w0 = (const float*)d_in[1];
  const float* w1 = (const float*)d_in[2];
  const float* w2 = (const float*)d_in[3];
  float* out = (float*)d_out;

  char* ws = (char*)d_ws;
  float* scal = (float*)ws;                    // [0]=D, [1]=total_loss
  float* partials = (float*)(ws + 1024);       // 1024 floats
  u16* xb = (u16*)(ws + 8192);                           // 16M elems (32MB)
  u16* w0t = xb + (size_t)B_SZ * S_SZ * H_SZ;            // 4M (8MB)
  u16* w2t = w0t + (size_t)H_SZ * F_SZ;                  // 4M
  u16* w1t = w2t + (size_t)H_SZ * F_SZ;                  // 4M
  u16* hbuf = w1t + (size_t)F_SZ * H_SZ;                 // 8M elems (16MB)
  u16* pbuf = hbuf + (size_t)MCH * F_SZ;                 // NSPLIT*2M elems (16MB)

  k_init<<<1, 256, 0, stream>>>(scal);
  k_cvt_x<<<(B_SZ * S_SZ * H_SZ) / (256 * 8), 256, 0, stream>>>(x, xb);
  k_transpose_cvt<<<dim3(F_SZ / 32, H_SZ / 32), 256, 0, stream>>>(w0, w0t, H_SZ, F_SZ);
  k_transpose_cvt<<<dim3(H_SZ / 32, F_SZ / 32), 256, 0, stream>>>(w1, w1t, F_SZ, H_SZ);
  k_transpose_cvt<<<dim3(F_SZ / 32, H_SZ / 32), 256, 0, stream>>>(w2, w2t, H_SZ, F_SZ);

  float* lossout = out + (size_t)B_SZ * S_SZ * H_SZ;
  for (int c = 0; c < NCHUNK; c++) {
    k_gemm_gu<<<dim3(16, 64), 256, 0, stream>>>(xb, w0t, w2t, hbuf, scal, c);
    k_gemm_out<<<dim3(16, 16, NSPLIT), 256, 0, stream>>>(hbuf, w1t, pbuf);
    k_epilogue<<<1024, 256, 0, stream>>>(pbuf, x, out, scal, partials, c);
    k_update<<<1, 256, 0, stream>>>(scal, partials, lossout, c);
  }
}

// Round 5
// 606.361 us; speedup vs baseline: 1.2601x; 1.2601x over previous
//
#include <hip/hip_runtime.h>

typedef float f32x4 __attribute__((ext_vector_type(4)));
typedef short bf16x8 __attribute__((ext_vector_type(8)));
typedef unsigned short u16;

#define B_SZ 4
#define S_SZ 4096
#define H_SZ 1024
#define F_SZ 4096
#define CHUNK_SZ 512
#define NCHUNK 8
#define MCH 2048            // rows per chunk (B*CHUNK)
#define LRATE 0.001f
#define NSPLIT 4            // split-K factor for GEMM2

__device__ __forceinline__ u16 f2bf(float f) {
  unsigned u = __float_as_uint(f);
  u += 0x7FFFu + ((u >> 16) & 1u);   // round-to-nearest-even
  return (u16)(u >> 16);
}
__device__ __forceinline__ float bf2f(u16 u) {
  return __uint_as_float(((unsigned)u) << 16);
}

__device__ __forceinline__ void gload_lds16(const void* g, void* l) {
  __builtin_amdgcn_global_load_lds(
      (const __attribute__((address_space(1))) unsigned int*)g,
      (__attribute__((address_space(3))) unsigned int*)l, 16, 0, 0);
}

// ---------------- converts ----------------

__global__ __launch_bounds__(256) void k_init(float* scal) {
  if (threadIdx.x == 0) { scal[0] = 1.f; scal[1] = 0.f; }
}

__global__ __launch_bounds__(256) void k_cvt_x(const float* __restrict__ x,
                                               u16* __restrict__ xb) {
  size_t i = ((size_t)blockIdx.x * 256 + threadIdx.x) * 8;
  float4 v0 = *(const float4*)(x + i);
  float4 v1 = *(const float4*)(x + i + 4);
  union { u16 u[8]; bf16x8 v; } o;
  o.u[0] = f2bf(v0.x); o.u[1] = f2bf(v0.y); o.u[2] = f2bf(v0.z); o.u[3] = f2bf(v0.w);
  o.u[4] = f2bf(v1.x); o.u[5] = f2bf(v1.y); o.u[6] = f2bf(v1.z); o.u[7] = f2bf(v1.w);
  *(bf16x8*)(xb + i) = o.v;
}

// W [R][C] fp32  ->  Wt [C][R] bf16
__global__ __launch_bounds__(256) void k_transpose_cvt(const float* __restrict__ W,
                                                       u16* __restrict__ Wt,
                                                       int R, int C) {
  __shared__ float tile[32][33];
  int tx = threadIdx.x & 31, ty = threadIdx.x >> 5;
  int r0 = blockIdx.y << 5, c0 = blockIdx.x << 5;
#pragma unroll
  for (int i = 0; i < 4; i++)
    tile[ty + i * 8][tx] = W[(size_t)(r0 + ty + i * 8) * C + c0 + tx];
  __syncthreads();
#pragma unroll
  for (int i = 0; i < 4; i++)
    Wt[(size_t)(c0 + ty + i * 8) * R + r0 + tx] = f2bf(tile[tx][ty + i * 8]);
}

// ---------------- GEMM 1: G = Xc@W0, U = Xc@W2, fused SwiGLU -> h (bf16) ----------------
// tile 128(M) x 128(N) DUAL-OUTPUT, BK=64, single-buffered 2-barrier loop (R2 schedule),
// XOR-swizzled LDS (pre-swizzled source), XCD-bijective block swizzle.
// Per wave: 64x64 of G AND U -> 128 acc regs, 64 MFMA per K-step vs 12 staging loads.
__global__ __launch_bounds__(256, 2) void k_gemm_gu(
    const u16* __restrict__ xb,   // [B][S][H] bf16
    const u16* __restrict__ w0t,  // [F][H] bf16 (w0^T)
    const u16* __restrict__ w2t,  // [F][H]
    u16* __restrict__ hbuf,       // [2048][F] bf16
    const float* __restrict__ scal, int chunk) {
  __shared__ __align__(16) u16 sA[128 * 64];    // 16KB
  __shared__ __align__(16) u16 sB0[128 * 64];   // 16KB
  __shared__ __align__(16) u16 sB2[128 * 64];   // 16KB

  int t = threadIdx.x;
  int lane = t & 63, wid = t >> 6;
  int wm = wid >> 1, wn = wid & 1;

  // XCD-bijective swizzle: 512 wgs / 8 XCDs -> contiguous 64-wg chunk per XCD
  int orig = blockIdx.x + (gridDim.x * blockIdx.y);
  int nwg = gridDim.x * gridDim.y;      // 512
  int wg = (orig & 7) * (nwg >> 3) + (orig >> 3);
  int tm = wg & 15, tn = wg >> 4;       // tm 0..15, tn 0..31

  int gm0 = tm << 7;               // chunk-local row 0 of tile
  int bb = gm0 >> 9;               // batch (tile never crosses batch)
  int pos0 = gm0 & 511;
  const u16* Abase = xb + ((size_t)bb * S_SZ + (size_t)chunk * CHUNK_SZ + pos0) * H_SZ;

  // staging (row = 128B = 8 slots of 16B): thread t -> row t>>3 (+32r), slot t&7.
  // source col = (slot ^ (row&7))*8 so LDS[row][slot] holds global col (slot^(row&7)).
  int srow = t >> 3;
  int scol = (((t & 7) ^ (srow & 7)) << 3);   // elements
  const u16* aSrc  = Abase + (size_t)srow * H_SZ + scol;
  const u16* b0Src = w0t + ((size_t)(tn << 7) + srow) * H_SZ + scol;
  const u16* b2Src = w2t + ((size_t)(tn << 7) + srow) * H_SZ + scol;
  char* aDst  = (char*)sA  + t * 16;
  char* b0Dst = (char*)sB0 + t * 16;
  char* b2Dst = (char*)sB2 + t * 16;

  f32x4 acc0[4][4], acc2[4][4];
#pragma unroll
  for (int i = 0; i < 4; i++)
#pragma unroll
    for (int j = 0; j < 4; j++)
#pragma unroll
      for (int k = 0; k < 4; k++) { acc0[i][j][k] = 0.f; acc2[i][j][k] = 0.f; }

  // fragment read offsets (swizzled): row&7 == lane&7 for all fr/fc
  int arow = (wm << 6) + (lane & 15);
  int brow = (wn << 6) + (lane & 15);
  int sl0 = (lane >> 4) ^ (lane & 7);
  int sl1 = ((lane >> 4) | 4) ^ (lane & 7);
  const int aO0 = arow * 128 + sl0 * 16, aO1 = arow * 128 + sl1 * 16;
  const int bO0 = brow * 128 + sl0 * 16, bO1 = brow * 128 + sl1 * 16;

#pragma unroll 1
  for (int k0 = 0; k0 < H_SZ; k0 += 64) {
#pragma unroll
    for (int r = 0; r < 4; r++) {
      gload_lds16(aSrc  + (size_t)r * 32 * H_SZ, aDst  + r * 4096);
      gload_lds16(b0Src + (size_t)r * 32 * H_SZ, b0Dst + r * 4096);
      gload_lds16(b2Src + (size_t)r * 32 * H_SZ, b2Dst + r * 4096);
    }
    aSrc += 64; b0Src += 64; b2Src += 64;
    __syncthreads();

    {
      bf16x8 av[4], b0v[4], b2v[4];
#pragma unroll
      for (int fr = 0; fr < 4; fr++) av[fr] = *(const bf16x8*)((const char*)sA + aO0 + fr * 2048);
#pragma unroll
      for (int fc = 0; fc < 4; fc++) {
        b0v[fc] = *(const bf16x8*)((const char*)sB0 + bO0 + fc * 2048);
        b2v[fc] = *(const bf16x8*)((const char*)sB2 + bO0 + fc * 2048);
      }
#pragma unroll
      for (int fr = 0; fr < 4; fr++)
#pragma unroll
        for (int fc = 0; fc < 4; fc++) {
          acc0[fr][fc] = __builtin_amdgcn_mfma_f32_16x16x32_bf16(av[fr], b0v[fc], acc0[fr][fc], 0, 0, 0);
          acc2[fr][fc] = __builtin_amdgcn_mfma_f32_16x16x32_bf16(av[fr], b2v[fc], acc2[fr][fc], 0, 0, 0);
        }
    }
    {
      bf16x8 av[4], b0v[4], b2v[4];
#pragma unroll
      for (int fr = 0; fr < 4; fr++) av[fr] = *(const bf16x8*)((const char*)sA + aO1 + fr * 2048);
#pragma unroll
      for (int fc = 0; fc < 4; fc++) {
        b0v[fc] = *(const bf16x8*)((const char*)sB0 + bO1 + fc * 2048);
        b2v[fc] = *(const bf16x8*)((const char*)sB2 + bO1 + fc * 2048);
      }
#pragma unroll
      for (int fr = 0; fr < 4; fr++)
#pragma unroll
        for (int fc = 0; fc < 4; fc++) {
          acc0[fr][fc] = __builtin_amdgcn_mfma_f32_16x16x32_bf16(av[fr], b0v[fc], acc0[fr][fc], 0, 0, 0);
          acc2[fr][fc] = __builtin_amdgcn_mfma_f32_16x16x32_bf16(av[fr], b2v[fc], acc2[fr][fc], 0, 0, 0);
        }
    }
    __syncthreads();
  }

  float D = scal[0];
#pragma unroll
  for (int fr = 0; fr < 4; fr++)
#pragma unroll
    for (int fc = 0; fc < 4; fc++) {
      int row0 = (tm << 7) + (wm << 6) + (fr << 4) + ((lane >> 4) << 2);
      int col = (tn << 7) + (wn << 6) + (fc << 4) + (lane & 15);
#pragma unroll
      for (int j = 0; j < 4; j++) {
        float g = D * acc0[fr][fc][j];
        float u = D * acc2[fr][fc][j];
        float sil = g / (1.f + __expf(-g));
        hbuf[(size_t)(row0 + j) * F_SZ + col] = f2bf(sil * u);
      }
    }
}

// ---------------- GEMM 2 (split-K): pbuf[kz] = h[:,kz*1024:+1024] @ w1t slice ----------------
// EXACT R2 config: tile 128x64, BK=64 single-buffered, swizzled LDS, no XCD remap.
__global__ __launch_bounds__(256) void k_gemm_out(
    const u16* __restrict__ hbuf,  // [2048][F]
    const u16* __restrict__ w1t,   // [H][F] (w1^T)
    u16* __restrict__ pbuf) {      // [NSPLIT][2048][1024] bf16 partials
  __shared__ __align__(16) u16 sA[128 * 64];
  __shared__ __align__(16) u16 sB[64 * 64];

  int t = threadIdx.x;
  int lane = t & 63, wid = t >> 6;
  int wm = wid >> 1, wn = wid & 1;
  int tm = blockIdx.x, tn = blockIdx.y, kz = blockIdx.z;

  int srow = t >> 3;
  int scol = (((t & 7) ^ (srow & 7)) << 3);
  const u16* aSrc = hbuf + ((size_t)(tm << 7) + srow) * F_SZ + kz * 1024 + scol;
  const u16* bSrc = w1t + ((size_t)(tn << 6) + srow) * F_SZ + kz * 1024 + scol;
  char* aDst = (char*)sA + t * 16;
  char* bDst = (char*)sB + t * 16;

  f32x4 acc[4][2];
#pragma unroll
  for (int i = 0; i < 4; i++)
#pragma unroll
    for (int j = 0; j < 2; j++)
#pragma unroll
      for (int k = 0; k < 4; k++) acc[i][j][k] = 0.f;

  int arow = (wm << 6) + (lane & 15);
  int brow = (wn << 5) + (lane & 15);
  int sl0 = (lane >> 4) ^ (lane & 7);
  int sl1 = ((lane >> 4) | 4) ^ (lane & 7);
  const int aO0 = arow * 128 + sl0 * 16, aO1 = arow * 128 + sl1 * 16;
  const int bO0 = brow * 128 + sl0 * 16, bO1 = brow * 128 + sl1 * 16;

#pragma unroll 1
  for (int k0 = 0; k0 < 1024; k0 += 64) {
#pragma unroll
    for (int r = 0; r < 4; r++)
      gload_lds16(aSrc + (size_t)r * 32 * F_SZ, aDst + r * 4096);
#pragma unroll
    for (int r = 0; r < 2; r++)
      gload_lds16(bSrc + (size_t)r * 32 * F_SZ, bDst + r * 4096);
    aSrc += 64; bSrc += 64;
    __syncthreads();

    {
      bf16x8 av[4], bv[2];
#pragma unroll
      for (int fr = 0; fr < 4; fr++) av[fr] = *(const bf16x8*)((const char*)sA + aO0 + fr * 2048);
#pragma unroll
      for (int fc = 0; fc < 2; fc++) bv[fc] = *(const bf16x8*)((const char*)sB + bO0 + fc * 2048);
#pragma unroll
      for (int fr = 0; fr < 4; fr++)
#pragma unroll
        for (int fc = 0; fc < 2; fc++)
          acc[fr][fc] = __builtin_amdgcn_mfma_f32_16x16x32_bf16(av[fr], bv[fc], acc[fr][fc], 0, 0, 0);
    }
    {
      bf16x8 av[4], bv[2];
#pragma unroll
      for (int fr = 0; fr < 4; fr++) av[fr] = *(const bf16x8*)((const char*)sA + aO1 + fr * 2048);
#pragma unroll
      for (int fc = 0; fc < 2; fc++) bv[fc] = *(const bf16x8*)((const char*)sB + bO1 + fc * 2048);
#pragma unroll
      for (int fr = 0; fr < 4; fr++)
#pragma unroll
        for (int fc = 0; fc < 2; fc++)
          acc[fr][fc] = __builtin_amdgcn_mfma_f32_16x16x32_bf16(av[fr], bv[fc], acc[fr][fc], 0, 0, 0);
    }
    __syncthreads();
  }

#pragma unroll
  for (int fr = 0; fr < 4; fr++)
#pragma unroll
    for (int fc = 0; fc < 2; fc++) {
      int row0 = (tm << 7) + (wm << 6) + (fr << 4) + ((lane >> 4) << 2);
      int col = (tn << 6) + (wn << 5) + (fc << 4) + (lane & 15);
#pragma unroll
      for (int j = 0; j < 4; j++)
        pbuf[((size_t)kz * MCH + row0 + j) * 1024 + col] = f2bf(acc[fr][fc][j]);
    }
}

// ---------------- epilogue: sum split-K partials, scale by D, write out, error reduce ----------------
__global__ __launch_bounds__(256) void k_epilogue(
    const u16* __restrict__ pbuf, const float* __restrict__ x,
    float* __restrict__ out, const float* __restrict__ scal,
    float* __restrict__ partials, int chunk) {
  __shared__ float red[256];
  int t = threadIdx.x;
  size_t base = ((size_t)blockIdx.x * 256 + t) * 8;   // elem index in [2048][1024]
  int row = (int)(base >> 10);
  int col = (int)(base & 1023);
  float D = scal[0];

  float s[8] = {0.f, 0.f, 0.f, 0.f, 0.f, 0.f, 0.f, 0.f};
#pragma unroll
  for (int kz = 0; kz < NSPLIT; kz++) {
    union { bf16x8 v; u16 u[8]; } p;
    p.v = *(const bf16x8*)(pbuf + (size_t)kz * MCH * 1024 + base);
#pragma unroll
    for (int j = 0; j < 8; j++) s[j] += bf2f(p.u[j]);
  }

  int bb = row >> 9, pos = row & 511;
  size_t off = ((size_t)bb * S_SZ + (size_t)chunk * CHUNK_SZ + pos) * H_SZ + col;
  float4 x0 = *(const float4*)(x + off);
  float4 x1 = *(const float4*)(x + off + 4);
  float xv[8] = {x0.x, x0.y, x0.z, x0.w, x1.x, x1.y, x1.z, x1.w};
  float ov[8];
  float psum = 0.f;
#pragma unroll
  for (int j = 0; j < 8; j++) {
    ov[j] = D * s[j];
    float e = ov[j] - xv[j];
    psum += e * e;
  }
  *(float4*)(out + off) = make_float4(ov[0], ov[1], ov[2], ov[3]);
  *(float4*)(out + off + 4) = make_float4(ov[4], ov[5], ov[6], ov[7]);

  red[t] = psum;
  __syncthreads();
  for (int s2 = 128; s2 > 0; s2 >>= 1) {
    if (t < s2) red[t] += red[t + s2];
    __syncthreads();
  }
  if (t == 0) partials[blockIdx.x] = red[0];
}

// ---------------- scalar chain update ----------------
__global__ __launch_bounds__(256) void k_update(float* scal, const float* __restrict__ partials,
                                                float* lossout, int chunk) {
  __shared__ float red[256];
  int t = threadIdx.x;
  float s = 0.f;
  for (int i = t; i < 1024; i += 256) s += partials[i];
  red[t] = s;
  __syncthreads();
  for (int s2 = 128; s2 > 0; s2 >>= 1) {
    if (t < s2) red[t] += red[t + s2];
    __syncthreads();
  }
  if (t == 0) {
    float loss = red[0] / (float)((size_t)MCH * H_SZ);
    float total = scal[1] + loss;
    scal[1] = total;
    scal[0] = scal[0] * (1.f - LRATE * loss);
    if (chunk == NCHUNK - 1) lossout[0] = total / (float)NCHUNK;
  }
}

// ---------------- launch ----------------
extern "C" void kernel_launch(void* const* d_in, const int* in_sizes, int n_in,
                              void* d_out, int out_size, void* d_ws, size_t ws_size,
                              hipStream_t stream) {
  const float* x = (const float*)d_in[0];
  const float* w0 = (const float*)d_in[1];
  const float* w1 = (const float*)d_in[2];
  const float* w2 = (const float*)d_in[3];
  float* out = (float*)d_out;

  char* ws = (char*)d_ws;
  float* scal = (float*)ws;                    // [0]=D, [1]=total_loss
  float* partials = (float*)(ws + 1024);       // 1024 floats
  u16* xb = (u16*)(ws + 8192);                           // 16M elems (32MB)
  u16* w0t = xb + (size_t)B_SZ * S_SZ * H_SZ;            // 4M (8MB)
  u16* w2t = w0t + (size_t)H_SZ * F_SZ;                  // 4M
  u16* w1t = w2t + (size_t)H_SZ * F_SZ;                  // 4M
  u16* hbuf = w1t + (size_t)F_SZ * H_SZ;                 // 8M elems (16MB)
  u16* pbuf = hbuf + (size_t)MCH * F_SZ;                 // NSPLIT*2M elems (16MB)

  k_init<<<1, 256, 0, stream>>>(scal);
  k_cvt_x<<<(B_SZ * S_SZ * H_SZ) / (256 * 8), 256, 0, stream>>>(x, xb);
  k_transpose_cvt<<<dim3(F_SZ / 32, H_SZ / 32), 256, 0, stream>>>(w0, w0t, H_SZ, F_SZ);
  k_transpose_cvt<<<dim3(H_SZ / 32, F_SZ / 32), 256, 0, stream>>>(w1, w1t, F_SZ, H_SZ);
  k_transpose_cvt<<<dim3(F_SZ / 32, H_SZ / 32), 256, 0, stream>>>(w2, w2t, H_SZ, F_SZ);

  float* lossout = out + (size_t)B_SZ * S_SZ * H_SZ;
  for (int c = 0; c < NCHUNK; c++) {
    k_gemm_gu<<<dim3(16, 32), 256, 0, stream>>>(xb, w0t, w2t, hbuf, scal, c);
    k_gemm_out<<<dim3(16, 16, NSPLIT), 256, 0, stream>>>(hbuf, w1t, pbuf);
    k_epilogue<<<1024, 256, 0, stream>>>(pbuf, x, out, scal, partials, c);
    k_update<<<1, 256, 0, stream>>>(scal, partials, lossout, c);
  }
}